// Round 12
// baseline (150.190 us; speedup 1.0000x reference)
//
#include <hip/hip_runtime.h>
#include <hip/hip_bf16.h>

#define S_ 8192
#define H_ 8
#define D_ 64
#define M_ 64
#define BH_ 32
#define CPK_ 80          // buf1/partial row stride (c 0..79, den at c=64)
#define MC_ (M_ * CPK_)
#define NCHQ 16
#define TILE 64
#define QTILES (S_ / NCHQ / TILE)   // 8

typedef short bf16x8 __attribute__((ext_vector_type(8)));
typedef float f32x4 __attribute__((ext_vector_type(4)));

constexpr float XS_ = 0.35355339059327373f * 1.4426950408889634f; // D^-1/4 * log2(e)
constexpr float HS_ = 0.34657359027997264f;                        // ln2/2
constexpr float EPS_ = 1e-6f;

__device__ __forceinline__ unsigned short f2bf(float f) {
    unsigned int u = __float_as_uint(f);
    u += 0x7FFFu + ((u >> 16) & 1u);          // RNE
    return (unsigned short)(u >> 16);
}
__device__ __forceinline__ unsigned int pkbf(float lo, float hi) {
    __hip_bfloat162 t = __float22bfloat162_rn(float2{lo, hi});
    return *reinterpret_cast<unsigned int*>(&t);
}
__device__ __forceinline__ float fexp2(float x) { return __builtin_amdgcn_exp2f(x); }

#define MFMA(a, b, c) __builtin_amdgcn_mfma_f32_16x16x32_bf16((a), (b), (c), 0, 0, 0)
#define SWZ(byteoff, row) ((byteoff) ^ (((row) & 7) << 4))

// ===========================================================================
// ABLATION A: pure-load, dense-coalesced. 512 blocks x 256 thr; each thread
// sums 32 float4 of k and 32 of v at stride 128K f4 (fully coalesced).
// ===========================================================================
__global__ void __launch_bounds__(256)
ab_dense(const float* __restrict__ ks, const float* __restrict__ vs,
         float* __restrict__ dig)
{
    const int bid = blockIdx.y * 16 + blockIdx.x;
    const size_t t = (size_t)bid * 256 + threadIdx.x;        // [0, 131072)
    const float4* k4 = (const float4*)ks;
    const float4* v4 = (const float4*)vs;
    float s0 = 0.f, s1 = 0.f, s2 = 0.f, s3 = 0.f;
#pragma unroll
    for (int j = 0; j < 32; j += 4) {
        float4 a0 = k4[t + (size_t)(j + 0) * 131072];
        float4 a1 = k4[t + (size_t)(j + 1) * 131072];
        float4 a2 = k4[t + (size_t)(j + 2) * 131072];
        float4 a3 = k4[t + (size_t)(j + 3) * 131072];
        s0 += a0.x + a0.y + a0.z + a0.w;
        s1 += a1.x + a1.y + a1.z + a1.w;
        s2 += a2.x + a2.y + a2.z + a2.w;
        s3 += a3.x + a3.y + a3.z + a3.w;
    }
#pragma unroll
    for (int j = 0; j < 32; j += 4) {
        float4 a0 = v4[t + (size_t)(j + 0) * 131072];
        float4 a1 = v4[t + (size_t)(j + 1) * 131072];
        float4 a2 = v4[t + (size_t)(j + 2) * 131072];
        float4 a3 = v4[t + (size_t)(j + 3) * 131072];
        s0 += a0.x + a0.y + a0.z + a0.w;
        s1 += a1.x + a1.y + a1.z + a1.w;
        s2 += a2.x + a2.y + a2.z + a2.w;
        s3 += a3.x + a3.y + a3.z + a3.w;
    }
    dig[t] = (s0 + s1) + (s2 + s3);
}

// ===========================================================================
// ABLATION B: pure-load with fa_k's EXACT strided addressing (same rows,
// same 4xfloat4 offsets, k-pass then v-pass per 64-row group), sum digest.
// ===========================================================================
__global__ void __launch_bounds__(256)
ab_stride(const float* __restrict__ ks, const float* __restrict__ vs,
          float* __restrict__ dig)
{
    const int bh = blockIdx.y;
    const int b = bh >> 3, h = bh & 7;
    const int tid = threadIdx.x, wid = tid >> 6, lane = tid & 63;
    const int l15 = lane & 15, g = lane >> 4;
    const int cw = blockIdx.x * 4 + wid;
    const size_t rs = (size_t)H_ * D_;
    const float* kb = ks + ((size_t)b * S_ * H_ + h) * D_;
    const float* vb = vs + ((size_t)b * S_ * H_ + h) * D_;

    float s0 = 0.f, s1 = 0.f, s2 = 0.f, s3 = 0.f;
#pragma unroll
    for (int g2 = 0; g2 < 2; ++g2) {
        const int rbase = cw * 128 + g2 * 64;
#pragma unroll
        for (int T = 0; T < 4; ++T) {
            const float* r_ = kb + (size_t)(rbase + T * 16 + l15) * rs;
            float4 x0 = *(const float4*)(r_ + g * 8);
            float4 x1 = *(const float4*)(r_ + g * 8 + 4);
            float4 x2 = *(const float4*)(r_ + 32 + g * 8);
            float4 x3 = *(const float4*)(r_ + 32 + g * 8 + 4);
            s0 += x0.x + x0.y + x0.z + x0.w;
            s1 += x1.x + x1.y + x1.z + x1.w;
            s2 += x2.x + x2.y + x2.z + x2.w;
            s3 += x3.x + x3.y + x3.z + x3.w;
        }
#pragma unroll
        for (int T = 0; T < 4; ++T) {
            const float* r_ = vb + (size_t)(rbase + T * 16 + l15) * rs;
            float4 x0 = *(const float4*)(r_ + g * 8);
            float4 x1 = *(const float4*)(r_ + g * 8 + 4);
            float4 x2 = *(const float4*)(r_ + 32 + g * 8);
            float4 x3 = *(const float4*)(r_ + 32 + g * 8 + 4);
            s0 += x0.x + x0.y + x0.z + x0.w;
            s1 += x1.x + x1.y + x1.z + x1.w;
            s2 += x2.x + x2.y + x2.z + x2.w;
            s3 += x3.x + x3.y + x3.z + x3.w;
        }
    }
    dig[(size_t)(blockIdx.y * 16 + blockIdx.x) * 256 + tid] =
        (s0 + s1) + (s2 + s3);
}

// ===========================================================================
// Phase K body (r11, verified) — templated: NOSHF=1 removes the 6 cross-lane
// bpermutes per tile (h becomes wrong; ablation-only), else byte-identical.
// ===========================================================================

// load one 16-row tile of stream BASE into 4 named float4 regs
#define XLOAD(BASE, T, X0, X1, X2, X3) do {                                  \
    const float* r_ = (BASE) + (size_t)(rbase + (T) * 16 + l15) * rs;        \
    X0 = *(const float4*)(r_ + g * 8);                                       \
    X1 = *(const float4*)(r_ + g * 8 + 4);                                   \
    X2 = *(const float4*)(r_ + 32 + g * 8);                                  \
    X3 = *(const float4*)(r_ + 32 + g * 8 + 4);                              \
    } while (0)

#define CONSK(T, X0, X1, X2, X3) do {                                        \
    float kx_[16];                                                           \
    kx_[0]=X0.x*XS_; kx_[1]=X0.y*XS_; kx_[2]=X0.z*XS_; kx_[3]=X0.w*XS_;      \
    kx_[4]=X1.x*XS_; kx_[5]=X1.y*XS_; kx_[6]=X1.z*XS_; kx_[7]=X1.w*XS_;      \
    kx_[8]=X2.x*XS_; kx_[9]=X2.y*XS_; kx_[10]=X2.z*XS_; kx_[11]=X2.w*XS_;    \
    kx_[12]=X3.x*XS_; kx_[13]=X3.y*XS_; kx_[14]=X3.z*XS_; kx_[15]=X3.w*XS_;  \
    float sq_ = 0.f;                                                         \
    _Pragma("unroll")                                                        \
    for (int j_ = 0; j_ < 16; ++j_) sq_ += kx_[j_] * kx_[j_];                \
    if (!NOSHF) {                                                            \
        sq_ += __shfl_xor(sq_, 16);                                          \
        sq_ += __shfl_xor(sq_, 32);                                          \
    }                                                                        \
    float hrow_ = sq_ * HS_ + 3.0f;                                          \
    union { bf16x8 v; unsigned int u[4]; } A0_, A1_;                         \
    _Pragma("unroll")                                                        \
    for (int i_ = 0; i_ < 4; ++i_) {                                         \
        A0_.u[i_] = pkbf(kx_[2 * i_], kx_[2 * i_ + 1]);                      \
        A1_.u[i_] = pkbf(kx_[8 + 2 * i_], kx_[9 + 2 * i_]);                  \
    }                                                                        \
    f32x4 pa_[4];                                                            \
    _Pragma("unroll")                                                        \
    for (int mt_ = 0; mt_ < 4; ++mt_) {                                      \
        pa_[mt_] = (f32x4){0.f, 0.f, 0.f, 0.f};                              \
        pa_[mt_] = MFMA(A0_.v, pf[mt_][0], pa_[mt_]);                        \
        pa_[mt_] = MFMA(A1_.v, pf[mt_][1], pa_[mt_]);                        \
    }                                                                        \
    float hr_[4];                                                            \
    _Pragma("unroll")                                                        \
    for (int r_ = 0; r_ < 4; ++r_)                                           \
        hr_[r_] = NOSHF ? hrow_ : __shfl(hrow_, 4 * g + r_);                 \
    _Pragma("unroll")                                                        \
    for (int mt_ = 0; mt_ < 4; ++mt_) {                                      \
        unsigned int u0_ = pkbf(fexp2(pa_[mt_][0] - hr_[0]),                 \
                                fexp2(pa_[mt_][1] - hr_[1]));                \
        unsigned int u1_ = pkbf(fexp2(pa_[mt_][2] - hr_[2]),                 \
                                fexp2(pa_[mt_][3] - hr_[3]));                \
        *(unsigned long long*)(eW + ((T) >> 1) * 4096 + mt_ * 1024           \
                               + lane * 16 + ((T) & 1) * 8) =                \
            (unsigned long long)u0_ | ((unsigned long long)u1_ << 32);       \
    } } while (0)

#define VSCAT(T, X0, X1, X2, X3) do {                                        \
    char* vp_ = vW + ((T) >> 1) * 4096;                                      \
    int slot2_ = 2 * (((l15 >> 2) & 3) * 8 + 4 * ((T) & 1) + (l15 & 3));     \
    float vv_[16];                                                           \
    vv_[0]=X0.x; vv_[1]=X0.y; vv_[2]=X0.z; vv_[3]=X0.w;                      \
    vv_[4]=X1.x; vv_[5]=X1.y; vv_[6]=X1.z; vv_[7]=X1.w;                      \
    vv_[8]=X2.x; vv_[9]=X2.y; vv_[10]=X2.z; vv_[11]=X2.w;                    \
    vv_[12]=X3.x; vv_[13]=X3.y; vv_[14]=X3.z; vv_[15]=X3.w;                  \
    _Pragma("unroll")                                                        \
    for (int p2_ = 0; p2_ < 4; ++p2_) {                                      \
        int cA_ = g * 8 + 2 * p2_;                                           \
        unsigned int pA_ = pkbf(vv_[2 * p2_], vv_[2 * p2_ + 1]);             \
        *(unsigned short*)(vp_ + cA_ * 64 + (slot2_ ^ ((cA_ & 3) << 4))) =   \
            (unsigned short)pA_;                                             \
        int cB_ = cA_ + 1;                                                   \
        *(unsigned short*)(vp_ + cB_ * 64 + (slot2_ ^ ((cB_ & 3) << 4))) =   \
            (unsigned short)(pA_ >> 16);                                     \
        int cC_ = 32 + cA_;                                                  \
        unsigned int pB_ = pkbf(vv_[8 + 2 * p2_], vv_[9 + 2 * p2_]);         \
        *(unsigned short*)(vp_ + cC_ * 64 + (slot2_ ^ ((cC_ & 3) << 4))) =   \
            (unsigned short)pB_;                                             \
        int cD_ = cC_ + 1;                                                   \
        *(unsigned short*)(vp_ + cD_ * 64 + (slot2_ ^ ((cD_ & 3) << 4))) =   \
            (unsigned short)(pB_ >> 16);                                     \
    } } while (0)

#define EVP(P) do {                                                          \
    bf16x8 eA_[4], vB_[4];                                                   \
    _Pragma("unroll")                                                        \
    for (int mt_ = 0; mt_ < 4; ++mt_)                                        \
        eA_[mt_] = *(const bf16x8*)(eW + (P) * 4096 + mt_ * 1024             \
                                    + lane * 16);                            \
    _Pragma("unroll")                                                        \
    for (int ct_ = 0; ct_ < 4; ++ct_) {                                      \
        int c_ = ct_ * 16 + l15;                                             \
        vB_[ct_] = *(const bf16x8*)(vW + (P) * 4096 + c_ * 64                \
                                    + ((16 * g) ^ ((c_ & 3) << 4)));         \
    }                                                                        \
    _Pragma("unroll")                                                        \
    for (int mt_ = 0; mt_ < 4; ++mt_) {                                      \
        _Pragma("unroll")                                                    \
        for (int ct_ = 0; ct_ < 4; ++ct_)                                    \
            acc[mt_][ct_] = MFMA(eA_[mt_], vB_[ct_], acc[mt_][ct_]);         \
        acc[mt_][4] = MFMA(eA_[mt_], onef, acc[mt_][4]);                     \
    } } while (0)

template<int NOSHF>
__device__ __forceinline__ void
fa_k_body(const float* __restrict__ ks, const float* __restrict__ vs,
          const float* __restrict__ proj, float* __restrict__ partial,
          int nch, int segs, char* eW, char* vW)
{
    const int bh = blockIdx.y;
    const int b = bh >> 3, h = bh & 7;
    const int tid = threadIdx.x, wid = tid >> 6, lane = tid & 63;
    const int l15 = lane & 15, g = lane >> 4;
    const int cw = blockIdx.x * 4 + wid;
    (void)tid; (void)wid;

    const size_t rs = (size_t)H_ * D_;
    const float* kb = ks + ((size_t)b * S_ * H_ + h) * D_;
    const float* vb = vs + ((size_t)b * S_ * H_ + h) * D_;

    bf16x8 pf[4][2];
#pragma unroll
    for (int mt = 0; mt < 4; ++mt)
#pragma unroll
        for (int kk = 0; kk < 2; ++kk) {
            const float* p = proj + (mt * 16 + l15) * D_ + kk * 32 + g * 8;
            float4 a = *(const float4*)p, c = *(const float4*)(p + 4);
            union { bf16x8 v; unsigned int u[4]; } F;
            F.u[0] = pkbf(a.x, a.y); F.u[1] = pkbf(a.z, a.w);
            F.u[2] = pkbf(c.x, c.y); F.u[3] = pkbf(c.z, c.w);
            pf[mt][kk] = F.v;
        }

    bf16x8 onef = {0, 0, 0, 0, 0, 0, 0, 0};
    if (l15 == 0) {
#pragma unroll
        for (int j = 0; j < 8; ++j) onef[j] = (short)0x3F80;
    }

    f32x4 acc[4][5];
#pragma unroll
    for (int mt = 0; mt < 4; ++mt)
#pragma unroll
        for (int ci = 0; ci < 5; ++ci) acc[mt][ci] = (f32x4){0.f, 0.f, 0.f, 0.f};

    for (int seg = 0; seg < segs; ++seg) {
#pragma unroll
        for (int g2 = 0; g2 < 2; ++g2) {
            const int rbase = cw * (128 * segs) + seg * 128 + g2 * 64;
            float4 a0, a1, a2, a3, b0, b1, b2, b3;

            // ---- PASS A: k stream only ----
            XLOAD(kb, 0, a0, a1, a2, a3);
            XLOAD(kb, 1, b0, b1, b2, b3);
            CONSK(0, a0, a1, a2, a3);
            XLOAD(kb, 2, a0, a1, a2, a3);
            CONSK(1, b0, b1, b2, b3);
            XLOAD(kb, 3, b0, b1, b2, b3);
            CONSK(2, a0, a1, a2, a3);
            CONSK(3, b0, b1, b2, b3);
            __builtin_amdgcn_sched_barrier(0);

            // ---- PASS B: v stream only ----
            XLOAD(vb, 0, a0, a1, a2, a3);
            XLOAD(vb, 1, b0, b1, b2, b3);
            VSCAT(0, a0, a1, a2, a3);
            XLOAD(vb, 2, a0, a1, a2, a3);
            VSCAT(1, b0, b1, b2, b3);
            XLOAD(vb, 3, b0, b1, b2, b3);
            EVP(0);
            VSCAT(2, a0, a1, a2, a3);
            VSCAT(3, b0, b1, b2, b3);
            EVP(1);
            __builtin_amdgcn_sched_barrier(0);
        }
    }

    float* dst = partial + ((size_t)bh * nch + cw) * MC_;
#pragma unroll
    for (int mt = 0; mt < 4; ++mt)
#pragma unroll
        for (int ct = 0; ct < 5; ++ct)
#pragma unroll
            for (int r = 0; r < 4; ++r)
                dst[(mt * 16 + 4 * g + r) * CPK_ + ct * 16 + l15] =
                    acc[mt][ct][r];
}

__global__ void __launch_bounds__(256, 2)
fa_k(const float* __restrict__ ks, const float* __restrict__ vs,
     const float* __restrict__ proj, float* __restrict__ partial,
     int nch, int segs)
{
    __shared__ __align__(16) char eL[4 * 8192];
    __shared__ __align__(16) char vL[4 * 8192];
    const int wid = threadIdx.x >> 6;
    fa_k_body<0>(ks, vs, proj, partial, nch, segs,
                 eL + wid * 8192, vL + wid * 8192);
}

// ABLATION C: full fa_k minus the 6 cross-lane bpermutes/tile (wrong h).
__global__ void __launch_bounds__(256, 2)
ab_noshfl(const float* __restrict__ ks, const float* __restrict__ vs,
          const float* __restrict__ proj, float* __restrict__ partial,
          int nch, int segs)
{
    __shared__ __align__(16) char eL[4 * 8192];
    __shared__ __align__(16) char vL[4 * 8192];
    const int wid = threadIdx.x >> 6;
    fa_k_body<1>(ks, vs, proj, partial, nch, segs,
                 eL + wid * 8192, vL + wid * 8192);
}

// ---------------------------------------------------------------------------
// Reduce partials over chunks -> buf1[bh][m][CPK_]
// ---------------------------------------------------------------------------
__global__ void __launch_bounds__(256)
fa_r(const float* __restrict__ partial, float* __restrict__ buf1, int nch)
{
    int e = blockIdx.x * 256 + threadIdx.x;
    if (e >= BH_ * MC_) return;
    int bh = e / MC_;
    int r  = e - bh * MC_;
    const float* src = partial + (size_t)bh * nch * MC_ + r;
    float s0 = 0.f, s1 = 0.f, s2 = 0.f, s3 = 0.f;
    int ch = 0;
    for (; ch + 4 <= nch; ch += 4) {
        s0 += src[(size_t)(ch + 0) * MC_];
        s1 += src[(size_t)(ch + 1) * MC_];
        s2 += src[(size_t)(ch + 2) * MC_];
        s3 += src[(size_t)(ch + 3) * MC_];
    }
    for (; ch < nch; ++ch) s0 += src[(size_t)ch * MC_];
    buf1[e] = (s0 + s1) + (s2 + s3);
}

// ---------------------------------------------------------------------------
// Phase Q: unchanged (r11). P = mfma(Qscaled, projT); e = exp2(P-h);
// D[c][qrow] = mfma(buf1T, E_T); den = c=64 row; out=num/den.
// ---------------------------------------------------------------------------
__global__ void __launch_bounds__(256)
fa_q(const float* __restrict__ qs, const float* __restrict__ proj,
     const float* __restrict__ buf1, float* __restrict__ out)
{
    const int chunk = blockIdx.x;
    const int bh    = blockIdx.y;
    const int b = bh >> 3, h = bh & 7;
    const int tid = threadIdx.x, wid = tid >> 6, lane = tid & 63;
    const int l15 = lane & 15, g = lane >> 4;

    __shared__ __align__(16) char eLb[2][TILE * M_ * 2];
    __shared__ __align__(16) char b1tb[CPK_ * M_ * 2];

    const int rows = S_ / NCHQ;
    const int s0 = chunk * rows;
    const size_t rs = (size_t)H_ * D_;
    const float* qb = qs + ((size_t)b * S_ * H_ + h) * D_;

    const float* b1 = buf1 + (size_t)bh * MC_;
    for (int i = tid; i < MC_; i += 256) {
        int m = i / CPK_, c = i - m * CPK_;
        *(unsigned short*)(b1tb + SWZ(c * 128 + 2 * m, c)) = f2bf(b1[i]);
    }

    bf16x8 pf[4][2];
#pragma unroll
    for (int mt = 0; mt < 4; ++mt)
#pragma unroll
        for (int kk = 0; kk < 2; ++kk) {
            const float* p = proj + (mt * 16 + l15) * D_ + kk * 32 + g * 8;
            float4 a = *(const float4*)p, c = *(const float4*)(p + 4);
            union { bf16x8 v; unsigned int u[4]; } F;
            F.u[0] = pkbf(a.x, a.y); F.u[1] = pkbf(a.z, a.w);
            F.u[2] = pkbf(c.x, c.y); F.u[3] = pkbf(c.z, c.w);
            pf[mt][kk] = F.v;
        }
    __syncthreads();

    bf16x8 af3[5][2];
#pragma unroll
    for (int ci = 0; ci < 5; ++ci)
#pragma unroll
        for (int kk = 0; kk < 2; ++kk) {
            int c = ci * 16 + l15;
            af3[ci][kk] = *(const bf16x8*)(b1tb + SWZ(c * 128 + 16 * g + 64 * kk, c));
        }

    auto loadQ = [&](int t, float4* qp) {
        int sb = s0 + t * TILE;
        const float* qrow = qb + (size_t)(sb + wid * 16 + l15) * rs;
        qp[0] = *(const float4*)(qrow + g * 8);
        qp[1] = *(const float4*)(qrow + g * 8 + 4);
        qp[2] = *(const float4*)(qrow + 32 + g * 8);
        qp[3] = *(const float4*)(qrow + 32 + g * 8 + 4);
    };

    auto body = [&](int t, int p, const float4* qc, float4* qn) {
        if (t + 1 < QTILES) loadQ(t + 1, qn);

        float kx[16];
#pragma unroll
        for (int i = 0; i < 4; ++i) {
            kx[4 * i + 0] = qc[i].x * XS_; kx[4 * i + 1] = qc[i].y * XS_;
            kx[4 * i + 2] = qc[i].z * XS_; kx[4 * i + 3] = qc[i].w * XS_;
        }
        float sq = 0.f;
#pragma unroll
        for (int j = 0; j < 16; ++j) sq += kx[j] * kx[j];
        sq += __shfl_xor(sq, 16);
        sq += __shfl_xor(sq, 32);
        float hrow = sq * HS_ + 3.0f;

        union { bf16x8 v; unsigned int u[4]; } A0, A1;
#pragma unroll
        for (int i = 0; i < 4; ++i) {
            A0.u[i] = pkbf(kx[2 * i], kx[2 * i + 1]);
            A1.u[i] = pkbf(kx[8 + 2 * i], kx[9 + 2 * i]);
        }

        f32x4 pa[4];
#pragma unroll
        for (int mt = 0; mt < 4; ++mt) {
            pa[mt] = (f32x4){0.f, 0.f, 0.f, 0.f};
            pa[mt] = MFMA(A0.v, pf[mt][0], pa[mt]);
            pa[mt] = MFMA(A1.v, pf[mt][1], pa[mt]);
        }

        float hr[4];
#pragma unroll
        for (int r = 0; r < 4; ++r) hr[r] = __shfl(hrow, 4 * g + r);

        char* elp = eLb[p];
#pragma unroll
        for (int mt = 0; mt < 4; ++mt) {
            int m = mt * 16 + l15;
            float e0 = fexp2(pa[mt][0] - hr[0]);
            float e1 = fexp2(pa[mt][1] - hr[1]);
            float e2 = fexp2(pa[mt][2] - hr[2]);
            float e3 = fexp2(pa[mt][3] - hr[3]);
            unsigned int p01 = pkbf(e0, e1), p23 = pkbf(e2, e3);
            int q0 = wid * 16 + 4 * g;
            *(unsigned short*)(elp + SWZ((q0 + 0) * 128 + 2 * m, q0 + 0)) =
                (unsigned short)p01;
            *(unsigned short*)(elp + SWZ((q0 + 1) * 128 + 2 * m, q0 + 1)) =
                (unsigned short)(p01 >> 16);
            *(unsigned short*)(elp + SWZ((q0 + 2) * 128 + 2 * m, q0 + 2)) =
                (unsigned short)p23;
            *(unsigned short*)(elp + SWZ((q0 + 3) * 128 + 2 * m, q0 + 3)) =
                (unsigned short)(p23 >> 16);
        }
        __syncthreads();

        bf16x8 b3[2];
        {
            int qrow = wid * 16 + l15;
            b3[0] = *(const bf16x8*)(elp + SWZ(qrow * 128 + 16 * g, qrow));
            b3[1] = *(const bf16x8*)(elp + SWZ(qrow * 128 + 16 * g + 64, qrow));
        }
        f32x4 dt[5];
#pragma unroll
        for (int ci = 0; ci < 5; ++ci) {
            dt[ci] = (f32x4){0.f, 0.f, 0.f, 0.f};
            dt[ci] = MFMA(af3[ci][0], b3[0], dt[ci]);
            dt[ci] = MFMA(af3[ci][1], b3[1], dt[ci]);
        }

        float den = __shfl(dt[4][0], l15);
        float rd = 1.0f / fmaxf(den, EPS_);

        int sg = s0 + t * TILE + wid * 16 + l15;
        size_t base = (((size_t)b * S_ + sg) * H_ + h) * D_;
#pragma unroll
        for (int ci = 0; ci < 4; ++ci) {
            f32x4 o;
#pragma unroll
            for (int r = 0; r < 4; ++r) o[r] = dt[ci][r] * rd;
            *(f32x4*)(out + base + ci * 16 + 4 * g) = o;
        }
    };

    float4 qa[4], qb2[4];
    loadQ(0, qa);
    for (int t = 0; t < QTILES; t += 2) {
        body(t, 0, qa, qb2);
        body(t + 1, 1, qb2, qa);
    }
}

extern "C" void kernel_launch(void* const* d_in, const int* in_sizes, int n_in,
                              void* d_out, int out_size, void* d_ws, size_t ws_size,
                              hipStream_t stream)
{
    const float* qs   = (const float*)d_in[0];
    const float* ks   = (const float*)d_in[1];
    const float* vs   = (const float*)d_in[2];
    const float* proj = (const float*)d_in[3];
    float* out = (float*)d_out;

    int segs = 1, nch = 64;
    if ((size_t)BH_ * (size_t)(nch + 1) * MC_ * sizeof(float) > ws_size) {
        segs = 2; nch = 32;
    }
    int gx = 16 / segs;

    float* partial = (float*)d_ws;                // BH*nch*MC_
    float* buf1 = partial + (size_t)BH_ * nch * MC_;

    // --- ablation dispatches (digests land inside `partial`, which the real
    // fa_k fully overwrites afterwards — zero correctness impact) ---
    ab_dense <<<dim3(16, BH_), 256, 0, stream>>>(ks, vs, partial);
    ab_stride<<<dim3(16, BH_), 256, 0, stream>>>(ks, vs, partial);
    ab_noshfl<<<dim3(gx, BH_), 256, 0, stream>>>(ks, vs, proj, partial, nch, segs);

    // --- real pipeline (byte-identical to r11) ---
    fa_k<<<dim3(gx, BH_), 256, 0, stream>>>(ks, vs, proj, partial, nch, segs);
    int nred = (BH_ * MC_ + 255) / 256;
    fa_r<<<dim3(nred), 256, 0, stream>>>(partial, buf1, nch);
    fa_q<<<dim3(NCHQ, BH_), 256, 0, stream>>>(qs, proj, buf1, out);
}

// Round 13
// 94.119 us; speedup vs baseline: 1.5957x; 1.5957x over previous
//
#include <hip/hip_runtime.h>
#include <hip/hip_bf16.h>

#define S_ 8192
#define H_ 8
#define D_ 64
#define M_ 64
#define BH_ 32
#define CPK_ 80          // buf1/partial row stride (c 0..79, den at c=64)
#define MC_ (M_ * CPK_)
#define NCHQ 32
#define TILE 64
#define QTILES (S_ / NCHQ / TILE)   // 4

typedef short bf16x8 __attribute__((ext_vector_type(8)));
typedef float f32x4 __attribute__((ext_vector_type(4)));

constexpr float XS_ = 0.35355339059327373f * 1.4426950408889634f; // D^-1/4 * log2(e)
constexpr float HS_ = 0.34657359027997264f;                        // ln2/2
constexpr float EPS_ = 1e-6f;

__device__ __forceinline__ unsigned short f2bf(float f) {
    unsigned int u = __float_as_uint(f);
    u += 0x7FFFu + ((u >> 16) & 1u);          // RNE
    return (unsigned short)(u >> 16);
}
// paired RNE conversion -> v_cvt_pk_bf16_f32 (lo in low 16 bits)
__device__ __forceinline__ unsigned int pkbf(float lo, float hi) {
    __hip_bfloat162 t = __float22bfloat162_rn(float2{lo, hi});
    return *reinterpret_cast<unsigned int*>(&t);
}
__device__ __forceinline__ float fexp2(float x) { return __builtin_amdgcn_exp2f(x); }

#define MFMA(a, b, c) __builtin_amdgcn_mfma_f32_16x16x32_bf16((a), (b), (c), 0, 0, 0)
#define SWZ(byteoff, row) ((byteoff) ^ (((row) & 7) << 4))

// ---------------------------------------------------------------------------
// Phase K — round-5 kernel (verified correct), now at 4x grid.
// r12 ablation: pure dense loads at 512 blocks = 2.7 TB/s (L3-resident!) ==
// the 12-round fa_k wall -> the limit was WAVE-LEVEL LOAD CONCURRENCY, not
// pattern/spills/barriers. This kernel: VGPR=100, LDS=32KB -> 5 blocks/CU;
// nch=64 gives 2048 blocks -> ~20 waves/CU (vs 5-8 in r3-r11).
// ---------------------------------------------------------------------------
__global__ void __launch_bounds__(256)
fa_k(const float* __restrict__ ks, const float* __restrict__ vs,
     const float* __restrict__ proj, float* __restrict__ partial,
     int nch, int ktiles)
{
    const int chunk = blockIdx.x;
    const int bh    = blockIdx.y;
    const int b = bh >> 3, h = bh & 7;
    const int tid = threadIdx.x, wid = tid >> 6, lane = tid & 63;
    const int l15 = lane & 15, g = lane >> 4;

    __shared__ __align__(16) char eTb[2][M_ * TILE * 2];   // [m][row] bf16, swz by m
    __shared__ __align__(16) char vTb[2][D_ * TILE * 2];   // [c][row] bf16, swz by c

    const int rows = ktiles * TILE;
    const int s0 = chunk * rows;
    const size_t rs = (size_t)H_ * D_;
    const float* kb = ks + ((size_t)b * S_ * H_ + h) * D_;
    const float* vb = vs + ((size_t)b * S_ * H_ + h) * D_;

    // proj B-fragments: B[k=d][n=m]: lane: m = mt*16+l15, d = g*8+j (+32*kk)
    bf16x8 pf[4][2];
#pragma unroll
    for (int mt = 0; mt < 4; ++mt)
#pragma unroll
        for (int kk = 0; kk < 2; ++kk) {
            const float* p = proj + (mt * 16 + l15) * D_ + kk * 32 + g * 8;
            float4 a = *(const float4*)p, c = *(const float4*)(p + 4);
            union { bf16x8 v; unsigned int u[4]; } F;
            F.u[0] = pkbf(a.x, a.y); F.u[1] = pkbf(a.z, a.w);
            F.u[2] = pkbf(c.x, c.y); F.u[3] = pkbf(c.z, c.w);
            pf[mt][kk] = F.v;
        }

    // ones-column B-frag (c-tile 4): B[k][c]=1 iff c==64  (lane l15==0)
    bf16x8 onef = {0, 0, 0, 0, 0, 0, 0, 0};
    if (l15 == 0) {
#pragma unroll
        for (int j = 0; j < 8; ++j) onef[j] = (short)0x3F80;
    }

    f32x4 acc[5];
#pragma unroll
    for (int ci = 0; ci < 5; ++ci) acc[ci] = (f32x4){0.f, 0.f, 0.f, 0.f};

    auto loadT = [&](int t, float4* kp, float4* vp) {
        int sb = s0 + t * TILE;
        const float* krow = kb + (size_t)(sb + wid * 16 + l15) * rs;
        kp[0] = *(const float4*)(krow + g * 8);
        kp[1] = *(const float4*)(krow + g * 8 + 4);
        kp[2] = *(const float4*)(krow + 32 + g * 8);
        kp[3] = *(const float4*)(krow + 32 + g * 8 + 4);
        const float* vrow = vb + (size_t)(sb + wid * 16 + l15) * rs;
        vp[0] = *(const float4*)(vrow + g * 8);
        vp[1] = *(const float4*)(vrow + g * 8 + 4);
        vp[2] = *(const float4*)(vrow + 32 + g * 8);
        vp[3] = *(const float4*)(vrow + 32 + g * 8 + 4);
    };

    auto body = [&](int t, int p, const float4* kc, const float4* vc,
                    float4* kn, float4* vn) {
        if (t + 1 < ktiles) loadT(t + 1, kn, vn);

        // scale + h for row (wid*16 + l15)
        float kx[16];
#pragma unroll
        for (int i = 0; i < 4; ++i) {
            kx[4 * i + 0] = kc[i].x * XS_; kx[4 * i + 1] = kc[i].y * XS_;
            kx[4 * i + 2] = kc[i].z * XS_; kx[4 * i + 3] = kc[i].w * XS_;
        }
        float sq = 0.f;
#pragma unroll
        for (int j = 0; j < 16; ++j) sq += kx[j] * kx[j];
        sq += __shfl_xor(sq, 16);
        sq += __shfl_xor(sq, 32);
        float hrow = sq * HS_ + 3.0f;

        union { bf16x8 v; unsigned int u[4]; } A0, A1;
#pragma unroll
        for (int i = 0; i < 4; ++i) {
            A0.u[i] = pkbf(kx[2 * i], kx[2 * i + 1]);
            A1.u[i] = pkbf(kx[8 + 2 * i], kx[9 + 2 * i]);
        }

        f32x4 pa[4];
#pragma unroll
        for (int mt = 0; mt < 4; ++mt) {
            pa[mt] = (f32x4){0.f, 0.f, 0.f, 0.f};
            pa[mt] = MFMA(A0.v, pf[mt][0], pa[mt]);
            pa[mt] = MFMA(A1.v, pf[mt][1], pa[mt]);
        }

        float hr[4];
#pragma unroll
        for (int r = 0; r < 4; ++r) hr[r] = __shfl(hrow, 4 * g + r);

        char* etp = eTb[p];
        char* vtp = vTb[p];
#pragma unroll
        for (int mt = 0; mt < 4; ++mt) {
            float e0 = fexp2(pa[mt][0] - hr[0]);
            float e1 = fexp2(pa[mt][1] - hr[1]);
            float e2 = fexp2(pa[mt][2] - hr[2]);
            float e3 = fexp2(pa[mt][3] - hr[3]);
            unsigned long long pk = (unsigned long long)pkbf(e0, e1)
                                  | ((unsigned long long)pkbf(e2, e3) << 32);
            int m = mt * 16 + l15;
            *(unsigned long long*)(etp + SWZ(m * 128 + 32 * wid + 8 * g, m)) = pk;
        }
        {
            // transpose v into vT[c][row]: 16 u16 scatter stores
            int row = wid * 16 + l15;
            float vv[16];
#pragma unroll
            for (int i = 0; i < 4; ++i) {
                vv[4 * i + 0] = vc[i].x; vv[4 * i + 1] = vc[i].y;
                vv[4 * i + 2] = vc[i].z; vv[4 * i + 3] = vc[i].w;
            }
#pragma unroll
            for (int q = 0; q < 4; ++q) {
                int c0 = g * 8 + 2 * q;
                unsigned int pA = pkbf(vv[2 * q], vv[2 * q + 1]);
                *(unsigned short*)(vtp + SWZ(c0 * 128 + 2 * row, c0)) =
                    (unsigned short)pA;
                *(unsigned short*)(vtp + SWZ((c0 + 1) * 128 + 2 * row, c0 + 1)) =
                    (unsigned short)(pA >> 16);
                int c1 = 32 + c0;
                unsigned int pB = pkbf(vv[8 + 2 * q], vv[9 + 2 * q]);
                *(unsigned short*)(vtp + SWZ(c1 * 128 + 2 * row, c1)) =
                    (unsigned short)pB;
                *(unsigned short*)(vtp + SWZ((c1 + 1) * 128 + 2 * row, c1 + 1)) =
                    (unsigned short)(pB >> 16);
            }
        }
        __syncthreads();

        bf16x8 a2[2];
        {
            int m = wid * 16 + l15;
            a2[0] = *(const bf16x8*)(etp + SWZ(m * 128 + 16 * g, m));
            a2[1] = *(const bf16x8*)(etp + SWZ(m * 128 + 16 * g + 64, m));
        }
#pragma unroll
        for (int ci = 0; ci < 4; ++ci) {
            int c = ci * 16 + l15;
            bf16x8 b0 = *(const bf16x8*)(vtp + SWZ(c * 128 + 16 * g, c));
            bf16x8 b1 = *(const bf16x8*)(vtp + SWZ(c * 128 + 16 * g + 64, c));
            acc[ci] = MFMA(a2[0], b0, acc[ci]);
            acc[ci] = MFMA(a2[1], b1, acc[ci]);
        }
        acc[4] = MFMA(a2[0], onef, acc[4]);
        acc[4] = MFMA(a2[1], onef, acc[4]);
    };

    float4 ka[4], kb2[4];
    float4 va[4], vb2[4];
    loadT(0, ka, va);
    for (int t = 0; t + 2 <= ktiles; t += 2) {
        body(t, 0, ka, va, kb2, vb2);
        body(t + 1, 1, kb2, vb2, ka, va);
    }

    // store partials: D[m][c]: m = wid*16 + 4g + r, c = ci*16 + l15
    float* dst = partial + ((size_t)bh * nch + chunk) * MC_;
#pragma unroll
    for (int ci = 0; ci < 5; ++ci)
#pragma unroll
        for (int r = 0; r < 4; ++r)
            dst[(wid * 16 + 4 * g + r) * CPK_ + ci * 16 + l15] = acc[ci][r];
}

// ---------------------------------------------------------------------------
// Reduce partials over chunks -> buf1[bh][m][CPK_]
// ---------------------------------------------------------------------------
__global__ void __launch_bounds__(256)
fa_r(const float* __restrict__ partial, float* __restrict__ buf1, int nch)
{
    int e = blockIdx.x * 256 + threadIdx.x;
    if (e >= BH_ * MC_) return;
    int bh = e / MC_;
    int r  = e - bh * MC_;
    const float* src = partial + (size_t)bh * nch * MC_ + r;
    float s0 = 0.f, s1 = 0.f, s2 = 0.f, s3 = 0.f;
    int ch = 0;
    for (; ch + 4 <= nch; ch += 4) {
        s0 += src[(size_t)(ch + 0) * MC_];
        s1 += src[(size_t)(ch + 1) * MC_];
        s2 += src[(size_t)(ch + 2) * MC_];
        s3 += src[(size_t)(ch + 3) * MC_];
    }
    for (; ch < nch; ++ch) s0 += src[(size_t)ch * MC_];
    buf1[e] = (s0 + s1) + (s2 + s3);
}

// ---------------------------------------------------------------------------
// Phase Q: r11 kernel, NCHQ 16->32 (1024 blocks) for wave concurrency.
// ---------------------------------------------------------------------------
__global__ void __launch_bounds__(256)
fa_q(const float* __restrict__ qs, const float* __restrict__ proj,
     const float* __restrict__ buf1, float* __restrict__ out)
{
    const int chunk = blockIdx.x;
    const int bh    = blockIdx.y;
    const int b = bh >> 3, h = bh & 7;
    const int tid = threadIdx.x, wid = tid >> 6, lane = tid & 63;
    const int l15 = lane & 15, g = lane >> 4;

    __shared__ __align__(16) char eLb[2][TILE * M_ * 2];
    __shared__ __align__(16) char b1tb[CPK_ * M_ * 2];

    const int rows = S_ / NCHQ;
    const int s0 = chunk * rows;
    const size_t rs = (size_t)H_ * D_;
    const float* qb = qs + ((size_t)b * S_ * H_ + h) * D_;

    const float* b1 = buf1 + (size_t)bh * MC_;
    for (int i = tid; i < MC_; i += 256) {
        int m = i / CPK_, c = i - m * CPK_;
        *(unsigned short*)(b1tb + SWZ(c * 128 + 2 * m, c)) = f2bf(b1[i]);
    }

    bf16x8 pf[4][2];
#pragma unroll
    for (int mt = 0; mt < 4; ++mt)
#pragma unroll
        for (int kk = 0; kk < 2; ++kk) {
            const float* p = proj + (mt * 16 + l15) * D_ + kk * 32 + g * 8;
            float4 a = *(const float4*)p, c = *(const float4*)(p + 4);
            union { bf16x8 v; unsigned int u[4]; } F;
            F.u[0] = pkbf(a.x, a.y); F.u[1] = pkbf(a.z, a.w);
            F.u[2] = pkbf(c.x, c.y); F.u[3] = pkbf(c.z, c.w);
            pf[mt][kk] = F.v;
        }
    __syncthreads();

    bf16x8 af3[5][2];
#pragma unroll
    for (int ci = 0; ci < 5; ++ci)
#pragma unroll
        for (int kk = 0; kk < 2; ++kk) {
            int c = ci * 16 + l15;
            af3[ci][kk] = *(const bf16x8*)(b1tb + SWZ(c * 128 + 16 * g + 64 * kk, c));
        }

    auto loadQ = [&](int t, float4* qp) {
        int sb = s0 + t * TILE;
        const float* qrow = qb + (size_t)(sb + wid * 16 + l15) * rs;
        qp[0] = *(const float4*)(qrow + g * 8);
        qp[1] = *(const float4*)(qrow + g * 8 + 4);
        qp[2] = *(const float4*)(qrow + 32 + g * 8);
        qp[3] = *(const float4*)(qrow + 32 + g * 8 + 4);
    };

    auto body = [&](int t, int p, const float4* qc, float4* qn) {
        if (t + 1 < QTILES) loadQ(t + 1, qn);

        float kx[16];
#pragma unroll
        for (int i = 0; i < 4; ++i) {
            kx[4 * i + 0] = qc[i].x * XS_; kx[4 * i + 1] = qc[i].y * XS_;
            kx[4 * i + 2] = qc[i].z * XS_; kx[4 * i + 3] = qc[i].w * XS_;
        }
        float sq = 0.f;
#pragma unroll
        for (int j = 0; j < 16; ++j) sq += kx[j] * kx[j];
        sq += __shfl_xor(sq, 16);
        sq += __shfl_xor(sq, 32);
        float hrow = sq * HS_ + 3.0f;

        union { bf16x8 v; unsigned int u[4]; } A0, A1;
#pragma unroll
        for (int i = 0; i < 4; ++i) {
            A0.u[i] = pkbf(kx[2 * i], kx[2 * i + 1]);
            A1.u[i] = pkbf(kx[8 + 2 * i], kx[9 + 2 * i]);
        }

        f32x4 pa[4];
#pragma unroll
        for (int mt = 0; mt < 4; ++mt) {
            pa[mt] = (f32x4){0.f, 0.f, 0.f, 0.f};
            pa[mt] = MFMA(A0.v, pf[mt][0], pa[mt]);
            pa[mt] = MFMA(A1.v, pf[mt][1], pa[mt]);
        }

        float hr[4];
#pragma unroll
        for (int r = 0; r < 4; ++r) hr[r] = __shfl(hrow, 4 * g + r);

        char* elp = eLb[p];
#pragma unroll
        for (int mt = 0; mt < 4; ++mt) {
            int m = mt * 16 + l15;
            float e0 = fexp2(pa[mt][0] - hr[0]);
            float e1 = fexp2(pa[mt][1] - hr[1]);
            float e2 = fexp2(pa[mt][2] - hr[2]);
            float e3 = fexp2(pa[mt][3] - hr[3]);
            unsigned int p01 = pkbf(e0, e1), p23 = pkbf(e2, e3);
            int q0 = wid * 16 + 4 * g;
            *(unsigned short*)(elp + SWZ((q0 + 0) * 128 + 2 * m, q0 + 0)) =
                (unsigned short)p01;
            *(unsigned short*)(elp + SWZ((q0 + 1) * 128 + 2 * m, q0 + 1)) =
                (unsigned short)(p01 >> 16);
            *(unsigned short*)(elp + SWZ((q0 + 2) * 128 + 2 * m, q0 + 2)) =
                (unsigned short)p23;
            *(unsigned short*)(elp + SWZ((q0 + 3) * 128 + 2 * m, q0 + 3)) =
                (unsigned short)(p23 >> 16);
        }
        __syncthreads();

        bf16x8 b3[2];
        {
            int qrow = wid * 16 + l15;
            b3[0] = *(const bf16x8*)(elp + SWZ(qrow * 128 + 16 * g, qrow));
            b3[1] = *(const bf16x8*)(elp + SWZ(qrow * 128 + 16 * g + 64, qrow));
        }
        f32x4 dt[5];
#pragma unroll
        for (int ci = 0; ci < 5; ++ci) {
            dt[ci] = (f32x4){0.f, 0.f, 0.f, 0.f};
            dt[ci] = MFMA(af3[ci][0], b3[0], dt[ci]);
            dt[ci] = MFMA(af3[ci][1], b3[1], dt[ci]);
        }

        float den = __shfl(dt[4][0], l15);
        float rd = 1.0f / fmaxf(den, EPS_);

        int sg = s0 + t * TILE + wid * 16 + l15;
        size_t base = (((size_t)b * S_ + sg) * H_ + h) * D_;
#pragma unroll
        for (int ci = 0; ci < 4; ++ci) {
            f32x4 o;
#pragma unroll
            for (int r = 0; r < 4; ++r) o[r] = dt[ci][r] * rd;
            *(f32x4*)(out + base + ci * 16 + 4 * g) = o;
        }
    };

    float4 qa[4], qb2[4];
    loadQ(0, qa);
    for (int t = 0; t < QTILES; t += 2) {
        body(t, 0, qa, qb2);
        body(t + 1, 1, qb2, qa);
    }
}

extern "C" void kernel_launch(void* const* d_in, const int* in_sizes, int n_in,
                              void* d_out, int out_size, void* d_ws, size_t ws_size,
                              hipStream_t stream)
{
    const float* qs   = (const float*)d_in[0];
    const float* ks   = (const float*)d_in[1];
    const float* vs   = (const float*)d_in[2];
    const float* proj = (const float*)d_in[3];
    float* out = (float*)d_out;

    // nch=64 -> 2048 blocks (5 blocks/CU by LDS, ~20 waves/CU); 53MB partial
    int nch = 64;
    while (nch > 16 &&
           (size_t)BH_ * (size_t)(nch + 1) * MC_ * sizeof(float) > ws_size)
        nch >>= 1;
    int ktiles = S_ / nch / TILE;                 // 2 (or 4/8 on fallback)

    float* partial = (float*)d_ws;                // BH*nch*MC_
    float* buf1 = partial + (size_t)BH_ * nch * MC_;

    fa_k<<<dim3(nch, BH_), 256, 0, stream>>>(ks, vs, proj, partial, nch, ktiles);
    int nred = (BH_ * MC_ + 255) / 256;
    fa_r<<<dim3(nred), 256, 0, stream>>>(partial, buf1, nch);
    fa_q<<<dim3(NCHQ, BH_), 256, 0, stream>>>(qs, proj, buf1, out);
}